// Round 1
// baseline (334.980 us; speedup 1.0000x reference)
//
#include <hip/hip_runtime.h>

#define N_U 8192
#define N_V 8192
#define DIM 64
#define NR 5

typedef __attribute__((ext_vector_type(8))) short short8;
typedef __attribute__((ext_vector_type(4))) float f32x4;

__device__ inline unsigned short f2bf(float x) {
    unsigned u = __float_as_uint(x);
    return (unsigned short)((u + 0x7FFFu + ((u >> 16) & 1u)) >> 16);
}

// Fragment linear index (in shorts) for element (r, k, o) of a P table.
// Layout chosen so the GEMM's B-fragment load is one coalesced 16B read per lane:
//   lane = ((k>>2)&3)*16 + (o&15); j = ((k>>4)&1)*4 + (k&3); ktile = k>>5; n = o>>4
// (Any consistent (lanegroup,j)->k bijection is valid as long as the A-mask
//  builder uses the same map — permutations cancel inside the MFMA.)
__device__ inline size_t pfrag_idx(int r, int k, int o) {
    int ktile = k >> 5;
    int lane  = ((k >> 2) & 3) * 16 + (o & 15);
    int j     = ((k >> 4) & 1) * 4 + (k & 3);
    int n     = o >> 4;
    return ((((size_t)r * (N_V / 32) + ktile) * 4 + n) * 64 + lane) * 8 + j;
}

// ---------------- P precompute: P[r][v][o] = sum_f feat[v][f] * W[r][f][o] ----
// One wave per (dir, r, 32-v block). lane = o. W column held in regs,
// feat row broadcast via shfl. Output written bf16 in fragment order.
__global__ __launch_bounds__(256) void precompute_P(
    const float* __restrict__ u_feat, const float* __restrict__ v_feat,
    const float* __restrict__ w_u, const float* __restrict__ w_v,
    unsigned short* __restrict__ p_u, unsigned short* __restrict__ p_v)
{
    int wid  = (blockIdx.x * blockDim.x + threadIdx.x) >> 6;
    int lane = threadIdx.x & 63;
    const int tasks = 2 * NR * (N_V / 32);
    if (wid >= tasks) return;
    int dir  = wid / (NR * (N_V / 32));
    int rem  = wid % (NR * (N_V / 32));
    int r    = rem / (N_V / 32);
    int v0   = (rem % (N_V / 32)) * 32;

    const float* feat = dir ? u_feat : v_feat;   // dir 0: P_u uses v_feature
    const float* w    = dir ? w_v : w_u;
    unsigned short* dst = dir ? p_v : p_u;

    float wreg[DIM];
#pragma unroll
    for (int f = 0; f < DIM; ++f) wreg[f] = w[(r * DIM + f) * DIM + lane];

    for (int v = v0; v < v0 + 32; ++v) {
        float x = feat[(size_t)v * DIM + lane];
        float acc = 0.f;
#pragma unroll
        for (int f = 0; f < DIM; ++f) acc += __shfl(x, f) * wreg[f];
        dst[pfrag_idx(r, v, lane)] = f2bf(acc);
    }
}

// ---------------- masked GEMM ----------------
// out[row][o] += sum_r sum_k mask_r[row][k] * P[r][k][o]
// TRANS=0: row=u, k=v (reads adj row-major). TRANS=1: row=v, k=u (4x4 reg transpose).
// Block: 512 thr = 8 waves, each wave 32 rows (2 M-tiles). BM=256 rows/WG.
// Grid: (8192/256 row-blocks, 16 K-chunks of 512). f32 atomic partials.
// Degree counts accumulated in LDS during staging, one global atomic per row.
template <int TRANS>
__global__ __launch_bounds__(512) void gemm_masked(
    const int* __restrict__ adj, const unsigned short* __restrict__ pfrag,
    float* __restrict__ outp, unsigned int* __restrict__ deg)
{
    __shared__ unsigned char tile[256 * 72];  // [256 rows][64 k-bytes + 8 pad]
    __shared__ unsigned int cnt[256];

    const int tid  = threadIdx.x;
    const int lane = tid & 63;
    const int wv   = tid >> 6;
    const int b0   = blockIdx.x * 256;        // row-block base
    const int k0b  = blockIdx.y * 512;        // K-chunk base

    if (tid < 256) cnt[tid] = 0;
    __syncthreads();

    f32x4 acc[2][4];
#pragma unroll
    for (int m = 0; m < 2; ++m)
#pragma unroll
        for (int n = 0; n < 4; ++n) acc[m][n] = (f32x4){0.f, 0.f, 0.f, 0.f};

    for (int kk = 0; kk < 512; kk += 64) {
        const int k0 = k0b + kk;
        // ---- stage adj tile -> LDS int8 (+ degree counting) ----
        if (TRANS == 0) {
#pragma unroll
            for (int it = 0; it < 8; ++it) {
                int idx4 = it * 512 + tid;            // 4096 quads = 256x64 ints
                int row  = idx4 >> 4;
                int c4   = (idx4 & 15) * 4;
                int4 a = *(const int4*)(adj + (size_t)(b0 + row) * N_V + (k0 + c4));
                unsigned packed = (a.x & 0xFF) | ((a.y & 0xFF) << 8) |
                                  ((a.z & 0xFF) << 16) | ((a.w & 0xFF) << 24);
                *(unsigned*)&tile[row * 72 + c4] = packed;
                unsigned c = (a.x != 0) + (a.y != 0) + (a.z != 0) + (a.w != 0);
                if (c) atomicAdd(&cnt[row], c);
            }
        } else {
#pragma unroll
            for (int it = 0; it < 2; ++it) {
                int bi = it * 512 + tid;              // 1024 4x4 blocks (64u x 256v)
                int u4 = (bi >> 6) * 4;
                int v4 = (bi & 63) * 4;
                int4 d0 = *(const int4*)(adj + (size_t)(k0 + u4 + 0) * N_V + (b0 + v4));
                int4 d1 = *(const int4*)(adj + (size_t)(k0 + u4 + 1) * N_V + (b0 + v4));
                int4 d2 = *(const int4*)(adj + (size_t)(k0 + u4 + 2) * N_V + (b0 + v4));
                int4 d3 = *(const int4*)(adj + (size_t)(k0 + u4 + 3) * N_V + (b0 + v4));
                const int* p0 = (const int*)&d0; const int* p1 = (const int*)&d1;
                const int* p2 = (const int*)&d2; const int* p3 = (const int*)&d3;
#pragma unroll
                for (int c = 0; c < 4; ++c) {
                    int x0 = p0[c], x1 = p1[c], x2 = p2[c], x3 = p3[c];
                    unsigned packed = (x0 & 0xFF) | ((x1 & 0xFF) << 8) |
                                      ((x2 & 0xFF) << 16) | ((x3 & 0xFF) << 24);
                    *(unsigned*)&tile[(v4 + c) * 72 + u4] = packed;
                    unsigned cc = (x0 != 0) + (x1 != 0) + (x2 != 0) + (x3 != 0);
                    if (cc) atomicAdd(&cnt[v4 + c], cc);
                }
            }
        }
        __syncthreads();

        // ---- compute: two K=32 sub-steps ----
#pragma unroll
        for (int k32 = 0; k32 < 64; k32 += 32) {
            const int ktile = (k0 + k32) >> 5;
            short8 amask[2][NR];
#pragma unroll
            for (int m = 0; m < 2; ++m) {
                int row  = wv * 32 + m * 16 + (lane & 15);
                int boff = row * 72 + k32 + ((lane >> 4) << 2);
                unsigned d0 = *(const unsigned*)&tile[boff];
                unsigned d1 = *(const unsigned*)&tile[boff + 16];
#pragma unroll
                for (int rr = 0; rr < NR; ++rr) {
                    short8 msk;
#pragma unroll
                    for (int j = 0; j < 4; ++j)
                        msk[j] = (short)((((d0 >> (8 * j)) & 0xFFu) == (unsigned)(rr + 1)) ? 0x3F80 : 0);
#pragma unroll
                    for (int j = 0; j < 4; ++j)
                        msk[4 + j] = (short)((((d1 >> (8 * j)) & 0xFFu) == (unsigned)(rr + 1)) ? 0x3F80 : 0);
                    amask[m][rr] = msk;
                }
            }
#pragma unroll
            for (int n = 0; n < 4; ++n) {
#pragma unroll
                for (int rr = 0; rr < NR; ++rr) {
                    const unsigned short* bp =
                        pfrag + ((((size_t)rr * (N_V / 32) + ktile) * 4 + n) * 64 + lane) * 8;
                    short8 bfrag = *(const short8*)bp;
                    acc[0][n] = __builtin_amdgcn_mfma_f32_16x16x32_bf16(amask[0][rr], bfrag, acc[0][n], 0, 0, 0);
                    acc[1][n] = __builtin_amdgcn_mfma_f32_16x16x32_bf16(amask[1][rr], bfrag, acc[1][n], 0, 0, 0);
                }
            }
        }
        __syncthreads();
    }

    // ---- epilogue: atomic partial accumulate. C layout: col=lane&15, row=(lane>>4)*4+q ----
#pragma unroll
    for (int m = 0; m < 2; ++m) {
        int rbase = b0 + wv * 32 + m * 16 + ((lane >> 4) << 2);
#pragma unroll
        for (int n = 0; n < 4; ++n) {
#pragma unroll
            for (int q = 0; q < 4; ++q) {
                atomicAdd(&outp[(size_t)(rbase + q) * DIM + n * 16 + (lane & 15)], acc[m][n][q]);
            }
        }
    }
    if (tid < 256) atomicAdd(&deg[b0 + tid], cnt[tid]);
}

// ---------------- finalize: scale by 1/deg, ReLU ----------------
__global__ __launch_bounds__(256) void finalize_k(
    float* __restrict__ outp, const unsigned int* __restrict__ deg_u,
    const unsigned int* __restrict__ deg_v)
{
    int idx = blockIdx.x * blockDim.x + threadIdx.x;
    const int total = 2 * N_U * DIM;
    for (; idx < total; idx += gridDim.x * blockDim.x) {
        int row = idx >> 6;
        unsigned d = (row < N_U) ? deg_u[row] : deg_v[row - N_U];
        float s = d ? (1.f / (float)d) : 0.f;
        float v = outp[idx] * s;
        outp[idx] = v > 0.f ? v : 0.f;
    }
}

extern "C" void kernel_launch(void* const* d_in, const int* in_sizes, int n_in,
                              void* d_out, int out_size, void* d_ws, size_t ws_size,
                              hipStream_t stream)
{
    const int*   adj = (const int*)d_in[0];
    const float* uf  = (const float*)d_in[1];
    const float* vf  = (const float*)d_in[2];
    const float* wu  = (const float*)d_in[3];
    const float* wv  = (const float*)d_in[4];
    float* outp = (float*)d_out;

    unsigned char* ws = (unsigned char*)d_ws;
    const size_t P_BYTES = (size_t)NR * (N_V / 32) * 4 * 64 * 8 * 2;  // 5,242,880
    unsigned short* p_u  = (unsigned short*)ws;
    unsigned short* p_v  = (unsigned short*)(ws + P_BYTES);
    unsigned int*   deg_u = (unsigned int*)(ws + 2 * P_BYTES);
    unsigned int*   deg_v = (unsigned int*)(ws + 2 * P_BYTES + N_U * sizeof(unsigned int));

    // zero accumulators (harness does not re-zero between replays)
    hipMemsetAsync(d_out, 0, (size_t)2 * N_U * DIM * sizeof(float), stream);
    hipMemsetAsync(ws + 2 * P_BYTES, 0, (N_U + N_V) * sizeof(unsigned int), stream);

    precompute_P<<<640, 256, 0, stream>>>(uf, vf, wu, wv, p_u, p_v);

    dim3 grid(32, 16);
    gemm_masked<0><<<grid, 512, 0, stream>>>(adj, p_u, outp, deg_u);
    gemm_masked<1><<<grid, 512, 0, stream>>>(adj, p_v, outp + (size_t)N_U * DIM, deg_v);

    finalize_k<<<2048, 256, 0, stream>>>(outp, deg_u, deg_v);
}